// Round 1
// baseline (319.370 us; speedup 1.0000x reference)
//
#include <hip/hip_runtime.h>
#include <math.h>

#define T_DIM 64
#define NROWS_TOTAL 65536   // B*T = 1024*64
#define ROWS 32             // rows per mlp block

__device__ __forceinline__ float wave_reduce_add(float v) {
    #pragma unroll
    for (int off = 32; off > 0; off >>= 1) v += __shfl_xor(v, off, 64);
    return v;
}
__device__ __forceinline__ float wave_reduce_max(float v) {
    #pragma unroll
    for (int off = 32; off > 0; off >>= 1) v = fmaxf(v, __shfl_xor(v, off, 64));
    return v;
}

// One wave per (b,i) row; lane j = agent j (T==64==wave size).
__global__ __launch_bounds__(256) void attn_kernel(
    const float* __restrict__ state,
    const float* __restrict__ Wq,
    const float* __restrict__ Wk,
    const float* __restrict__ Wv,
    float* __restrict__ att_out)
{
    const int lane = threadIdx.x & 63;
    const int wave = threadIdx.x >> 6;
    const int row  = blockIdx.x * 4 + wave;   // b*T + i
    const int i    = row & (T_DIM - 1);
    const int b    = row >> 6;

    const float4* sp4 = (const float4*)(state + ((size_t)(b * T_DIM + lane)) * 8);
    float4 sa = sp4[0];
    float4 sb = sp4[1];
    float s0 = sa.x, s1 = sa.y, s2 = sa.z, s3 = sa.w, s7 = sb.w;

    // broadcast state[b,i,:] from lane i
    float si0 = __shfl(s0, i, 64), si1 = __shfl(s1, i, 64);
    float si2 = __shfl(s2, i, 64), si3 = __shfl(s3, i, 64);
    float si4 = __shfl(sb.x, i, 64), si5 = __shfl(sb.y, i, 64);
    float si6 = __shfl(sb.z, i, 64), si7 = __shfl(s7, i, 64);

    // q[15] = state[b,i,:] @ Wq  (Wq is 8x15 row-major)
    float q[15];
    #pragma unroll
    for (int m = 0; m < 15; ++m)
        q[m] = si0*Wq[m]      + si1*Wq[15+m]  + si2*Wq[30+m] + si3*Wq[45+m]
             + si4*Wq[60+m]   + si5*Wq[75+m]  + si6*Wq[90+m] + si7*Wq[105+m];

    // relative geometry, rotated by angle of agent j (per reference broadcast)
    float d0 = s0 - si0, d1 = s1 - si1, d2 = s2 - si2, d3 = s3 - si3;
    float ang = 1.5707963267948966f - s7;
    float sn, cs;
    sincosf(ang, &sn, &cs);
    float xn0 = d0*cs - d1*sn;
    float yn0 = d0*sn + d1*cs;
    float xn1 = d2*cs - d3*sn;
    float yn1 = d2*sn + d3*cs;
    float r = sqrtf(xn0*xn0 + yn0*yn0);
    const bool self = (lane == i);
    float inv_r = self ? 0.0f : (1.0f / r);
    float rt = 1.0f / (1.0f + expf(5.0f*r - 2.0f));   // sigmoid(2 - 5r)
    float f0 = xn0*inv_r, f1 = yn0*inv_r, f2 = xn1, f3 = yn1, f4 = rt;

    // keys/vals: rel_n(5) @ Wk/Wv (5x15 row-major)
    float key[15], val[15];
    #pragma unroll
    for (int m = 0; m < 15; ++m) {
        key[m] = f0*Wk[m] + f1*Wk[15+m] + f2*Wk[30+m] + f3*Wk[45+m] + f4*Wk[60+m];
        val[m] = f0*Wv[m] + f1*Wv[15+m] + f2*Wv[30+m] + f3*Wv[45+m] + f4*Wv[60+m];
    }

    const float inv_sqrt5 = 0.44721359549995794f;
    float w[3];
    #pragma unroll
    for (int h = 0; h < 3; ++h) {
        float sc = key[h*5+0]*q[h*5+0] + key[h*5+1]*q[h*5+1] + key[h*5+2]*q[h*5+2]
                 + key[h*5+3]*q[h*5+3] + key[h*5+4]*q[h*5+4];
        sc = self ? -INFINITY : sc * inv_sqrt5;
        float mx = wave_reduce_max(sc);
        float e = self ? 0.0f : expf(sc - mx);
        float su = wave_reduce_add(e);
        w[h] = e / su;
    }

    float att[15];
    #pragma unroll
    for (int m = 0; m < 15; ++m)
        att[m] = wave_reduce_add(w[m/5] * val[m]);

    if (lane == 0) {
        float* po = att_out + (size_t)row * 15;
        #pragma unroll
        for (int m = 0; m < 15; ++m) po[m] = att[m];
    }
}

__global__ __launch_bounds__(256) void mlp_kernel(
    const float* __restrict__ state,
    const float* __restrict__ noise,
    const float* __restrict__ att,
    const float* __restrict__ W1, const float* __restrict__ b1,
    const float* __restrict__ W2, const float* __restrict__ b2,
    const float* __restrict__ Wmu, const float* __restrict__ bmu,
    const float* __restrict__ Wls, const float* __restrict__ bls,
    float* __restrict__ action_out, float* __restrict__ logprob_out)
{
    __shared__ float x0[ROWS][24];     // [att(15) | state(8)] per row
    __shared__ float h1s[ROWS][256];   // writes lane-consecutive, reads wave-uniform -> conflict-free
    const int t = threadIdx.x;
    const int row0 = blockIdx.x * ROWS;

    for (int idx = t; idx < ROWS*15; idx += 256) {
        int r = idx / 15, e = idx - r*15;
        x0[r][e] = att[(size_t)(row0 + r)*15 + e];
    }
    if (t < ROWS*8) {
        int r = t >> 3, d = t & 7;
        x0[r][15 + d] = state[(size_t)(row0 + r)*8 + d];
    }
    __syncthreads();

    // phase 1: h1 = relu(x0 @ W1 + b1); thread t owns column c=t for all rows
    {
        const int c = t;
        float w1c[23];
        #pragma unroll
        for (int k = 0; k < 23; ++k) w1c[k] = W1[k*256 + c];
        const float bias = b1[c];
        for (int r = 0; r < ROWS; ++r) {
            float acc = bias;
            #pragma unroll
            for (int k = 0; k < 23; ++k) acc += x0[r][k] * w1c[k];
            h1s[r][c] = fmaxf(acc, 0.0f);
        }
    }
    __syncthreads();

    // phase 2: h2 = relu(h1 @ W2 + b2); micro-tile 8 rows x 4 cols per thread
    const int cg = t & 63;     // col group: cols c4..c4+3
    const int rg = t >> 6;     // wave id: rows rg*8..rg*8+7
    const int c4 = cg * 4;
    const int rbase = rg * 8;
    float acc[8][4];
    #pragma unroll
    for (int j = 0; j < 8; ++j)
        #pragma unroll
        for (int c = 0; c < 4; ++c) acc[j][c] = 0.0f;

    const float4* W2v = (const float4*)W2;   // W2[k][c4..c4+3] = W2v[k*64 + cg]
    for (int k = 0; k < 256; k += 4) {
        float4 w0 = W2v[(k+0)*64 + cg];
        float4 w1 = W2v[(k+1)*64 + cg];
        float4 w2 = W2v[(k+2)*64 + cg];
        float4 w3 = W2v[(k+3)*64 + cg];
        #pragma unroll
        for (int j = 0; j < 8; ++j) {
            float4 h = *(const float4*)&h1s[rbase + j][k];
            acc[j][0] += h.x*w0.x + h.y*w1.x + h.z*w2.x + h.w*w3.x;
            acc[j][1] += h.x*w0.y + h.y*w1.y + h.z*w2.y + h.w*w3.y;
            acc[j][2] += h.x*w0.z + h.y*w1.z + h.z*w2.z + h.w*w3.z;
            acc[j][3] += h.x*w0.w + h.y*w1.w + h.z*w2.w + h.w*w3.w;
        }
    }

    // phase 3: head partials + wave reduction + epilogue
    float4 bb   = *(const float4*)&b2[c4];
    float4 wm01 = *(const float4*)&Wmu[c4*2];      // cols c4,c4+1 x {o0,o1}
    float4 wm23 = *(const float4*)&Wmu[c4*2 + 4];  // cols c4+2,c4+3
    float4 wl01 = *(const float4*)&Wls[c4*2];
    float4 wl23 = *(const float4*)&Wls[c4*2 + 4];

    float pm0[8], pm1[8], pl0[8], pl1[8];
    #pragma unroll
    for (int j = 0; j < 8; ++j) {
        float h0 = fmaxf(acc[j][0] + bb.x, 0.0f);
        float h1_ = fmaxf(acc[j][1] + bb.y, 0.0f);
        float h2_ = fmaxf(acc[j][2] + bb.z, 0.0f);
        float h3 = fmaxf(acc[j][3] + bb.w, 0.0f);
        pm0[j] = h0*wm01.x + h1_*wm01.z + h2_*wm23.x + h3*wm23.z;
        pm1[j] = h0*wm01.y + h1_*wm01.w + h2_*wm23.y + h3*wm23.w;
        pl0[j] = h0*wl01.x + h1_*wl01.z + h2_*wl23.x + h3*wl23.z;
        pl1[j] = h0*wl01.y + h1_*wl01.w + h2_*wl23.y + h3*wl23.w;
    }
    #pragma unroll
    for (int off = 32; off > 0; off >>= 1) {
        #pragma unroll
        for (int j = 0; j < 8; ++j) {
            pm0[j] += __shfl_xor(pm0[j], off, 64);
            pm1[j] += __shfl_xor(pm1[j], off, 64);
            pl0[j] += __shfl_xor(pl0[j], off, 64);
            pl1[j] += __shfl_xor(pl1[j], off, 64);
        }
    }

    if ((t & 63) == 0) {
        const float bmu0 = bmu[0], bmu1 = bmu[1];
        const float bls0 = bls[0], bls1 = bls[1];
        #pragma unroll
        for (int j = 0; j < 8; ++j) {
            int row = row0 + rbase + j;
            float n0 = noise[(size_t)row*2 + 0];
            float n1 = noise[(size_t)row*2 + 1];
            float lp = 0.0f;
            {
                float mu = tanhf(pm0[j] + bmu0);
                float ls = tanhf(pl0[j] + bls0);
                ls = -20.0f + 11.0f * (ls + 1.0f);
                float sd = expf(ls);
                float a = tanhf(mu + sd*n0);
                action_out[(size_t)row*2 + 0] = a;
                lp += -0.5f*n0*n0 - ls - 0.9189385332046727f - logf(1.0f - a*a + 1e-7f);
            }
            {
                float mu = tanhf(pm1[j] + bmu1);
                float ls = tanhf(pl1[j] + bls1);
                ls = -20.0f + 11.0f * (ls + 1.0f);
                float sd = expf(ls);
                float a = tanhf(mu + sd*n1);
                action_out[(size_t)row*2 + 1] = a;
                lp += -0.5f*n1*n1 - ls - 0.9189385332046727f - logf(1.0f - a*a + 1e-7f);
            }
            logprob_out[row] = lp;
        }
    }
}

extern "C" void kernel_launch(void* const* d_in, const int* in_sizes, int n_in,
                              void* d_out, int out_size, void* d_ws, size_t ws_size,
                              hipStream_t stream)
{
    (void)in_sizes; (void)n_in; (void)out_size; (void)ws_size;
    const float* state = (const float*)d_in[0];
    const float* noise = (const float*)d_in[1];
    const float* Wq  = (const float*)d_in[2];
    const float* Wk  = (const float*)d_in[3];
    const float* Wv  = (const float*)d_in[4];
    const float* W1  = (const float*)d_in[5];
    const float* b1  = (const float*)d_in[6];
    const float* W2  = (const float*)d_in[7];
    const float* b2  = (const float*)d_in[8];
    const float* Wmu = (const float*)d_in[9];
    const float* bmu = (const float*)d_in[10];
    const float* Wls = (const float*)d_in[11];
    const float* bls = (const float*)d_in[12];

    float* att_ws = (float*)d_ws;                    // 65536*15 floats = 3.93 MB
    float* action_out  = (float*)d_out;              // B*T*2
    float* logprob_out = (float*)d_out + NROWS_TOTAL*2;  // B*T*1

    attn_kernel<<<NROWS_TOTAL/4, 256, 0, stream>>>(state, Wq, Wk, Wv, att_ws);
    mlp_kernel<<<NROWS_TOTAL/ROWS, 256, 0, stream>>>(state, noise, att_ws,
        W1, b1, W2, b2, Wmu, bmu, Wls, bls, action_out, logprob_out);
}

// Round 2
// 243.017 us; speedup vs baseline: 1.3142x; 1.3142x over previous
//
#include <hip/hip_runtime.h>
#include <math.h>

#define T_DIM 64
#define NROWS 65536   // B*T
#define MROWS 32      // rows per mlp block

typedef short bf16x8 __attribute__((ext_vector_type(8)));
typedef float f32x4  __attribute__((ext_vector_type(4)));

__device__ __forceinline__ unsigned short f2bf(float x){
    unsigned int u = __float_as_uint(x);
    u += 0x7FFFu + ((u >> 16) & 1u);      // RNE
    return (unsigned short)(u >> 16);
}
__device__ __forceinline__ float bf2f(unsigned short h){
    return __uint_as_float(((unsigned int)h) << 16);
}
__device__ __forceinline__ float wred_add(float v){
    #pragma unroll
    for (int off = 32; off > 0; off >>= 1) v += __shfl_xor(v, off, 64);
    return v;
}
__device__ __forceinline__ float wred_max(float v){
    #pragma unroll
    for (int off = 32; off > 0; off >>= 1) v = fmaxf(v, __shfl_xor(v, off, 64));
    return v;
}

// ---- prep: W2 (256x256 f32 row-major) -> W2T bf16 (256x256, [col][k]) ----
__global__ __launch_bounds__(256) void prep_kernel(const float* __restrict__ W2,
                                                   unsigned short* __restrict__ w2t){
    int r = blockIdx.x;        // k index
    int c = threadIdx.x;       // col index
    w2t[c * 256 + r] = f2bf(W2[r * 256 + c]);   // coalesced read, strided bf16 write (L2)
}

// ---- qk: per row fold q@Wk -> qk[h][f] so attention scores are 5-FMA dots ----
__global__ __launch_bounds__(256) void qk_kernel(const float* __restrict__ state,
                                                 const float* __restrict__ Wq,
                                                 const float* __restrict__ Wk,
                                                 float* __restrict__ qk_ws){
    int row = blockIdx.x * 256 + threadIdx.x;
    const float4* sp = (const float4*)(state + (size_t)row * 8);
    float4 a = sp[0], b4 = sp[1];
    float s[8] = {a.x, a.y, a.z, a.w, b4.x, b4.y, b4.z, b4.w};
    float q[15];
    #pragma unroll
    for (int m = 0; m < 15; ++m){
        float acc = 0.f;
        #pragma unroll
        for (int d = 0; d < 8; ++d) acc += s[d] * Wq[d * 15 + m];
        q[m] = acc;
    }
    float* out = qk_ws + (size_t)row * 15;
    #pragma unroll
    for (int h = 0; h < 3; ++h){
        #pragma unroll
        for (int f = 0; f < 5; ++f){
            float acc = 0.f;
            #pragma unroll
            for (int kk = 0; kk < 5; ++kk) acc += Wk[f * 15 + h * 5 + kk] * q[h * 5 + kk];
            out[h * 5 + f] = acc;
        }
    }
}

// ---- attention: one wave per (b,i); lane j = other agent ----
__global__ __launch_bounds__(256) void attn_kernel(const float* __restrict__ state,
                                                   const float* __restrict__ qk_ws,
                                                   const float* __restrict__ Wv,
                                                   float* __restrict__ att_out){
    const int lane = threadIdx.x & 63;
    const int row  = blockIdx.x * 4 + (threadIdx.x >> 6);
    const int i    = row & (T_DIM - 1);
    const int b    = row >> 6;

    const float4* sp4 = (const float4*)(state + (size_t)(b * T_DIM + lane) * 8);
    float4 sa = sp4[0];
    float4 sb = sp4[1];
    const float* sip = state + (size_t)(b * T_DIM + i) * 8;   // wave-uniform
    float si0 = sip[0], si1 = sip[1], si2 = sip[2], si3 = sip[3];

    float d0 = sa.x - si0, d1 = sa.y - si1, d2 = sa.z - si2, d3 = sa.w - si3;
    float ang = 1.5707963267948966f - sb.w;
    float sn, cs;
    __sincosf(ang, &sn, &cs);
    float xn0 = d0 * cs - d1 * sn, yn0 = d0 * sn + d1 * cs;
    float xn1 = d2 * cs - d3 * sn, yn1 = d2 * sn + d3 * cs;
    float r2 = xn0 * xn0 + yn0 * yn0;
    const bool self = (lane == i);
    float inv_r = self ? 0.f : rsqrtf(r2);
    float r = r2 * inv_r;
    float rt = 1.f / (1.f + __expf(5.f * r - 2.f));   // sigmoid(2 - 5r)
    float f0 = xn0 * inv_r, f1 = yn0 * inv_r, f2 = xn1, f3 = yn1, f4 = rt;

    const float* qkp = qk_ws + (size_t)row * 15;
    float isu[3];
    float g[3][5];
    #pragma unroll
    for (int h = 0; h < 3; ++h){
        float sc = f0 * qkp[h*5] + f1 * qkp[h*5+1] + f2 * qkp[h*5+2]
                 + f3 * qkp[h*5+3] + f4 * qkp[h*5+4];
        sc *= 0.44721359549995794f;
        sc = self ? -INFINITY : sc;
        float mx = wred_max(sc);
        float e  = self ? 0.f : __expf(sc - mx);
        float su = wred_add(e);
        isu[h] = 1.f / su;
        g[h][0] = wred_add(e * f0);
        g[h][1] = wred_add(e * f1);
        g[h][2] = wred_add(e * f2);
        g[h][3] = wred_add(e * f3);
        g[h][4] = wred_add(e * f4);
    }

    if (lane < 15){
        const int h = (lane >= 10) ? 2 : ((lane >= 5) ? 1 : 0);
        float g0 = (h == 0) ? g[0][0] : ((h == 1) ? g[1][0] : g[2][0]);
        float g1 = (h == 0) ? g[0][1] : ((h == 1) ? g[1][1] : g[2][1]);
        float g2 = (h == 0) ? g[0][2] : ((h == 1) ? g[1][2] : g[2][2]);
        float g3 = (h == 0) ? g[0][3] : ((h == 1) ? g[1][3] : g[2][3]);
        float g4 = (h == 0) ? g[0][4] : ((h == 1) ? g[1][4] : g[2][4]);
        float gi = (h == 0) ? isu[0]  : ((h == 1) ? isu[1]  : isu[2]);
        float av = g0 * Wv[lane] + g1 * Wv[15 + lane] + g2 * Wv[30 + lane]
                 + g3 * Wv[45 + lane] + g4 * Wv[60 + lane];
        att_out[(size_t)row * 15 + lane] = av * gi;
    }
}

// ---- MLP: W1 fp32 VALU (small), W2 via bf16 MFMA, heads + epilogue fused ----
__global__ __launch_bounds__(256) void mlp_kernel(
    const float* __restrict__ state, const float* __restrict__ noise,
    const float* __restrict__ att,
    const float* __restrict__ W1, const float* __restrict__ b1,
    const unsigned short* __restrict__ w2t, const float* __restrict__ b2,
    const float* __restrict__ Wmu, const float* __restrict__ bmu,
    const float* __restrict__ Wls, const float* __restrict__ bls,
    float* __restrict__ action_out, float* __restrict__ logprob_out)
{
    __shared__ float x0[MROWS][24];
    // union buffer: h1 as bf16 stride 264 (A-frag b128-friendly), then h2 as bf16 stride 260
    __shared__ __align__(16) unsigned short hbuf[MROWS * 264];
    const int t = threadIdx.x;
    const int row0 = blockIdx.x * MROWS;

    for (int idx = t; idx < MROWS * 15; idx += 256){
        int r = idx / 15, e = idx - r * 15;
        x0[r][e] = att[(size_t)(row0 + r) * 15 + e];
    }
    if (t < MROWS * 8){
        int r = t >> 3, d = t & 7;
        x0[r][15 + d] = state[(size_t)(row0 + r) * 8 + d];
    }
    __syncthreads();

    // phase 1: h1 = relu(x0 @ W1 + b1), thread t = column t, store bf16
    {
        const int c = t;
        float w1c[23];
        #pragma unroll
        for (int k = 0; k < 23; ++k) w1c[k] = W1[k * 256 + c];
        const float bias = b1[c];
        for (int r = 0; r < MROWS; ++r){
            float a = bias;
            #pragma unroll
            for (int k = 0; k < 23; ++k) a += x0[r][k] * w1c[k];
            hbuf[r * 264 + c] = f2bf(fmaxf(a, 0.f));
        }
    }
    __syncthreads();

    // phase 2: h2 = relu(h1 @ W2 + b2) via mfma_f32_16x16x32_bf16
    const int lane = t & 63;
    const int w    = t >> 6;
    const int lm   = lane & 15;   // A row / B col / D col
    const int lq   = lane >> 4;   // k-subchunk / D row group
    bf16x8 afr[2][8];
    #pragma unroll
    for (int rt = 0; rt < 2; ++rt)
        #pragma unroll
        for (int kk = 0; kk < 8; ++kk)
            afr[rt][kk] = *(const bf16x8*)&hbuf[(rt * 16 + lm) * 264 + kk * 32 + lq * 8];
    __syncthreads();   // everyone done reading h1 before hbuf is reused for h2

    #pragma unroll
    for (int ci = 0; ci < 4; ++ci){
        const int ct = w * 4 + ci;
        f32x4 acc0 = {0.f, 0.f, 0.f, 0.f};
        f32x4 acc1 = {0.f, 0.f, 0.f, 0.f};
        const unsigned short* bp = w2t + (ct * 16 + lm) * 256 + lq * 8;
        #pragma unroll
        for (int kk = 0; kk < 8; ++kk){
            bf16x8 bfr = *(const bf16x8*)(bp + kk * 32);
            acc0 = __builtin_amdgcn_mfma_f32_16x16x32_bf16(afr[0][kk], bfr, acc0, 0, 0, 0);
            acc1 = __builtin_amdgcn_mfma_f32_16x16x32_bf16(afr[1][kk], bfr, acc1, 0, 0, 0);
        }
        float bb = b2[ct * 16 + lm];
        #pragma unroll
        for (int p = 0; p < 4; ++p){
            int r0 = lq * 4 + p;
            hbuf[r0        * 260 + ct * 16 + lm] = f2bf(fmaxf(acc0[p] + bb, 0.f));
            hbuf[(16 + r0) * 260 + ct * 16 + lm] = f2bf(fmaxf(acc1[p] + bb, 0.f));
        }
    }
    __syncthreads();

    // phase 3: heads. thread t: row = t>>3, col segment = (t&7)*32
    const int prow = t >> 3;
    const int seg  = t & 7;
    float m0 = 0.f, m1 = 0.f, l0 = 0.f, l1 = 0.f;
    const ushort4* hr4 = (const ushort4*)&hbuf[prow * 260 + seg * 32];
    #pragma unroll
    for (int jj = 0; jj < 8; ++jj){
        ushort4 hv = hr4[jj];
        int c0 = seg * 32 + jj * 4;
        float4 wmA = *(const float4*)&Wmu[c0 * 2];
        float4 wmB = *(const float4*)&Wmu[c0 * 2 + 4];
        float4 wlA = *(const float4*)&Wls[c0 * 2];
        float4 wlB = *(const float4*)&Wls[c0 * 2 + 4];
        float h0 = bf2f(hv.x), h1 = bf2f(hv.y), h2 = bf2f(hv.z), h3 = bf2f(hv.w);
        m0 += h0 * wmA.x + h1 * wmA.z + h2 * wmB.x + h3 * wmB.z;
        m1 += h0 * wmA.y + h1 * wmA.w + h2 * wmB.y + h3 * wmB.w;
        l0 += h0 * wlA.x + h1 * wlA.z + h2 * wlB.x + h3 * wlB.z;
        l1 += h0 * wlA.y + h1 * wlA.w + h2 * wlB.y + h3 * wlB.w;
    }
    #pragma unroll
    for (int off = 1; off < 8; off <<= 1){
        m0 += __shfl_xor(m0, off, 64);
        m1 += __shfl_xor(m1, off, 64);
        l0 += __shfl_xor(l0, off, 64);
        l1 += __shfl_xor(l1, off, 64);
    }
    if (seg == 0){
        int row = row0 + prow;
        float n0 = noise[(size_t)row * 2 + 0];
        float n1 = noise[(size_t)row * 2 + 1];
        float lp = 0.f;
        {
            float mu = tanhf(m0 + bmu[0]);
            float ls = tanhf(l0 + bls[0]);
            ls = -20.f + 11.f * (ls + 1.f);
            float sd = expf(ls);
            float a = tanhf(mu + sd * n0);
            action_out[(size_t)row * 2 + 0] = a;
            lp += -0.5f * n0 * n0 - ls - 0.9189385332046727f - logf(1.f - a * a + 1e-7f);
        }
        {
            float mu = tanhf(m1 + bmu[1]);
            float ls = tanhf(l1 + bls[1]);
            ls = -20.f + 11.f * (ls + 1.f);
            float sd = expf(ls);
            float a = tanhf(mu + sd * n1);
            action_out[(size_t)row * 2 + 1] = a;
            lp += -0.5f * n1 * n1 - ls - 0.9189385332046727f - logf(1.f - a * a + 1e-7f);
        }
        logprob_out[row] = lp;
    }
}

extern "C" void kernel_launch(void* const* d_in, const int* in_sizes, int n_in,
                              void* d_out, int out_size, void* d_ws, size_t ws_size,
                              hipStream_t stream)
{
    (void)in_sizes; (void)n_in; (void)out_size; (void)ws_size;
    const float* state = (const float*)d_in[0];
    const float* noise = (const float*)d_in[1];
    const float* Wq  = (const float*)d_in[2];
    const float* Wk  = (const float*)d_in[3];
    const float* Wv  = (const float*)d_in[4];
    const float* W1  = (const float*)d_in[5];
    const float* b1  = (const float*)d_in[6];
    const float* W2  = (const float*)d_in[7];
    const float* b2  = (const float*)d_in[8];
    const float* Wmu = (const float*)d_in[9];
    const float* bmu = (const float*)d_in[10];
    const float* Wls = (const float*)d_in[11];
    const float* bls = (const float*)d_in[12];

    float* att_ws = (float*)d_ws;                       // 983040 f32
    float* qk_ws  = att_ws + (size_t)NROWS * 15;        // 983040 f32
    unsigned short* w2t = (unsigned short*)(qk_ws + (size_t)NROWS * 15);  // 65536 bf16

    float* action_out  = (float*)d_out;
    float* logprob_out = (float*)d_out + (size_t)NROWS * 2;

    prep_kernel<<<256, 256, 0, stream>>>(W2, w2t);
    qk_kernel<<<NROWS / 256, 256, 0, stream>>>(state, Wq, Wk, qk_ws);
    attn_kernel<<<NROWS / 4, 256, 0, stream>>>(state, qk_ws, Wv, att_ws);
    mlp_kernel<<<NROWS / MROWS, 256, 0, stream>>>(state, noise, att_ws,
        W1, b1, w2t, b2, Wmu, bmu, Wls, bls, action_out, logprob_out);
}

// Round 3
// 192.614 us; speedup vs baseline: 1.6581x; 1.2617x over previous
//
#include <hip/hip_runtime.h>
#include <math.h>

#define T_DIM 64
#define NROWS 65536   // B*T
#define MROWS 32      // rows per mlp block

typedef short bf16x8 __attribute__((ext_vector_type(8)));
typedef float f32x4  __attribute__((ext_vector_type(4)));

__device__ __forceinline__ unsigned short f2bf(float x){
    unsigned int u = __float_as_uint(x);
    u += 0x7FFFu + ((u >> 16) & 1u);      // RNE
    return (unsigned short)(u >> 16);
}
__device__ __forceinline__ float bf2f(unsigned short h){
    return __uint_as_float(((unsigned int)h) << 16);
}

// ---- DPP wave reductions (VALU pipe, not LDS swizzle) ----
template<int CTRL, int RM>
__device__ __forceinline__ float dpp_add(float v){
    int m = __builtin_amdgcn_update_dpp(0, __float_as_int(v), CTRL, RM, 0xF, 1);
    return v + __int_as_float(m);
}
template<int CTRL, int RM>
__device__ __forceinline__ float dpp_maxs(float v){
    int m = __builtin_amdgcn_update_dpp(__float_as_int(v), __float_as_int(v), CTRL, RM, 0xF, 0);
    return fmaxf(v, __int_as_float(m));
}
// full-wave sum, result broadcast via readlane(63)
__device__ __forceinline__ float wsum64(float v){
    v = dpp_add<0x111, 0xF>(v);   // row_shr:1
    v = dpp_add<0x112, 0xF>(v);   // row_shr:2
    v = dpp_add<0x114, 0xF>(v);   // row_shr:4
    v = dpp_add<0x118, 0xF>(v);   // row_shr:8
    v = dpp_add<0x142, 0xA>(v);   // row_bcast:15 (rows 1,3)
    v = dpp_add<0x143, 0xC>(v);   // row_bcast:31 (rows 2,3)
    return __uint_as_float(__builtin_amdgcn_readlane(__float_as_uint(v), 63));
}
__device__ __forceinline__ float wmax64(float v){
    v = dpp_maxs<0x111, 0xF>(v);
    v = dpp_maxs<0x112, 0xF>(v);
    v = dpp_maxs<0x114, 0xF>(v);
    v = dpp_maxs<0x118, 0xF>(v);
    v = dpp_maxs<0x142, 0xA>(v);
    v = dpp_maxs<0x143, 0xC>(v);
    return __uint_as_float(__builtin_amdgcn_readlane(__float_as_uint(v), 63));
}

// ---- combined prep (w2t, w1t) + qk fold ----
__global__ __launch_bounds__(256) void prep_qk_kernel(
    const float* __restrict__ W2, const float* __restrict__ W1,
    const float* __restrict__ state, const float* __restrict__ Wq,
    const float* __restrict__ Wk,
    unsigned short* __restrict__ w2t, unsigned short* __restrict__ w1t,
    float* __restrict__ qk_ws)
{
    const int bx = blockIdx.x;
    if (bx < 256){
        // qk: per-row fold q@Wk -> qk[h][f]
        int row = bx * 256 + threadIdx.x;
        const float4* sp = (const float4*)(state + (size_t)row * 8);
        float4 a = sp[0], b4 = sp[1];
        float s[8] = {a.x, a.y, a.z, a.w, b4.x, b4.y, b4.z, b4.w};
        float q[15];
        #pragma unroll
        for (int m = 0; m < 15; ++m){
            float acc = 0.f;
            #pragma unroll
            for (int d = 0; d < 8; ++d) acc += s[d] * Wq[d * 15 + m];
            q[m] = acc;
        }
        float* out = qk_ws + (size_t)row * 15;
        #pragma unroll
        for (int h = 0; h < 3; ++h){
            #pragma unroll
            for (int f = 0; f < 5; ++f){
                float acc = 0.f;
                #pragma unroll
                for (int kk = 0; kk < 5; ++kk) acc += Wk[f * 15 + h * 5 + kk] * q[h * 5 + kk];
                out[h * 5 + f] = acc;
            }
        }
    } else if (bx < 512){
        // W2 (256x256) -> w2t bf16 [col][k]
        int r = bx - 256;
        int c = threadIdx.x;
        w2t[c * 256 + r] = f2bf(W2[r * 256 + c]);
    } else {
        // W1 (23x256) -> w1t bf16 [col][k=32 zero-padded]
        int c = threadIdx.x;
        #pragma unroll
        for (int k = 0; k < 32; ++k)
            w1t[c * 32 + k] = (k < 23) ? f2bf(W1[k * 256 + c]) : (unsigned short)0;
    }
}

// ---- attention: one wave per (b,i); DPP reductions; writes x0 bf16 row ----
__global__ __launch_bounds__(256) void attn_kernel(
    const float* __restrict__ state, const float* __restrict__ qk_ws,
    const float* __restrict__ Wv, unsigned short* __restrict__ x0_ws)
{
    const int lane = threadIdx.x & 63;
    const int row  = blockIdx.x * 4 + (threadIdx.x >> 6);
    const int i    = row & (T_DIM - 1);
    const int b    = row >> 6;

    const float4* sp4 = (const float4*)(state + (size_t)(b * T_DIM + lane) * 8);
    float4 sa = sp4[0];
    float4 sb = sp4[1];
    const float* sip = state + (size_t)(b * T_DIM + i) * 8;   // wave-uniform
    float si0 = sip[0], si1 = sip[1], si2 = sip[2], si3 = sip[3];

    float d0 = sa.x - si0, d1 = sa.y - si1, d2 = sa.z - si2, d3 = sa.w - si3;
    float ang = 1.5707963267948966f - sb.w;
    float sn, cs;
    __sincosf(ang, &sn, &cs);
    float xn0 = d0 * cs - d1 * sn, yn0 = d0 * sn + d1 * cs;
    float xn1 = d2 * cs - d3 * sn, yn1 = d2 * sn + d3 * cs;
    float r2 = xn0 * xn0 + yn0 * yn0;
    const bool self = (lane == i);
    float inv_r = self ? 0.f : rsqrtf(r2);
    float r = r2 * inv_r;
    float rt = 1.f / (1.f + __expf(5.f * r - 2.f));   // sigmoid(2 - 5r)
    float f0 = xn0 * inv_r, f1 = yn0 * inv_r, f2 = xn1, f3 = yn1, f4 = rt;

    const float* qkp = qk_ws + (size_t)row * 15;
    float isu[3], g[3][5];
    #pragma unroll
    for (int h = 0; h < 3; ++h){
        float sc = f0 * qkp[h*5] + f1 * qkp[h*5+1] + f2 * qkp[h*5+2]
                 + f3 * qkp[h*5+3] + f4 * qkp[h*5+4];
        sc *= 0.44721359549995794f;
        sc = self ? -INFINITY : sc;
        float mx = wmax64(sc);
        float e  = self ? 0.f : __expf(sc - mx);
        isu[h] = 1.f / wsum64(e);
        g[h][0] = wsum64(e * f0);
        g[h][1] = wsum64(e * f1);
        g[h][2] = wsum64(e * f2);
        g[h][3] = wsum64(e * f3);
        g[h][4] = wsum64(e * f4);
    }

    unsigned short xv = 0;
    if (lane < 15){
        const int h = (lane >= 10) ? 2 : ((lane >= 5) ? 1 : 0);
        float g0 = (h == 0) ? g[0][0] : ((h == 1) ? g[1][0] : g[2][0]);
        float g1 = (h == 0) ? g[0][1] : ((h == 1) ? g[1][1] : g[2][1]);
        float g2 = (h == 0) ? g[0][2] : ((h == 1) ? g[1][2] : g[2][2]);
        float g3 = (h == 0) ? g[0][3] : ((h == 1) ? g[1][3] : g[2][3]);
        float g4 = (h == 0) ? g[0][4] : ((h == 1) ? g[1][4] : g[2][4]);
        float gi = (h == 0) ? isu[0]  : ((h == 1) ? isu[1]  : isu[2]);
        float av = g0 * Wv[lane] + g1 * Wv[15 + lane] + g2 * Wv[30 + lane]
                 + g3 * Wv[45 + lane] + g4 * Wv[60 + lane];
        xv = f2bf(av * gi);
    } else if (lane < 23){
        xv = f2bf(sip[lane - 15]);   // x0[15..22] = state[0..7]
    }
    if (lane < 32) x0_ws[(size_t)row * 32 + lane] = xv;   // [23..31] zero pad
}

// ---- MLP: both layers via bf16 MFMA, heads + epilogue fused ----
__global__ __launch_bounds__(256) void mlp_kernel(
    const unsigned short* __restrict__ x0_ws, const float* __restrict__ noise,
    const unsigned short* __restrict__ w1t, const float* __restrict__ b1,
    const unsigned short* __restrict__ w2t, const float* __restrict__ b2,
    const float* __restrict__ Wmu, const float* __restrict__ bmu,
    const float* __restrict__ Wls, const float* __restrict__ bls,
    float* __restrict__ action_out, float* __restrict__ logprob_out)
{
    __shared__ __align__(16) unsigned short hbuf[MROWS * 264];  // h1 stride 264, then h2 stride 260
    const int t = threadIdx.x;
    const int lane = t & 63, w = t >> 6;
    const int lm = lane & 15, lq = lane >> 4;
    const int row0 = blockIdx.x * MROWS;

    // phase 1: h1 = relu(x0 @ W1 + b1) via MFMA (K=32, zero-padded)
    bf16x8 a0 = *(const bf16x8*)&x0_ws[(size_t)(row0 + lm) * 32 + lq * 8];
    bf16x8 a1 = *(const bf16x8*)&x0_ws[(size_t)(row0 + 16 + lm) * 32 + lq * 8];
    #pragma unroll
    for (int ci = 0; ci < 4; ++ci){
        const int ct = w * 4 + ci;
        bf16x8 bfr = *(const bf16x8*)&w1t[(ct * 16 + lm) * 32 + lq * 8];
        f32x4 c0 = {0.f, 0.f, 0.f, 0.f};
        f32x4 c1 = {0.f, 0.f, 0.f, 0.f};
        c0 = __builtin_amdgcn_mfma_f32_16x16x32_bf16(a0, bfr, c0, 0, 0, 0);
        c1 = __builtin_amdgcn_mfma_f32_16x16x32_bf16(a1, bfr, c1, 0, 0, 0);
        float bb = b1[ct * 16 + lm];
        #pragma unroll
        for (int p = 0; p < 4; ++p){
            hbuf[(lq * 4 + p) * 264 + ct * 16 + lm]      = f2bf(fmaxf(c0[p] + bb, 0.f));
            hbuf[(16 + lq * 4 + p) * 264 + ct * 16 + lm] = f2bf(fmaxf(c1[p] + bb, 0.f));
        }
    }
    __syncthreads();

    // phase 2: h2 = relu(h1 @ W2 + b2) via MFMA
    bf16x8 afr[2][8];
    #pragma unroll
    for (int rt = 0; rt < 2; ++rt)
        #pragma unroll
        for (int kk = 0; kk < 8; ++kk)
            afr[rt][kk] = *(const bf16x8*)&hbuf[(rt * 16 + lm) * 264 + kk * 32 + lq * 8];
    __syncthreads();   // hbuf will be reused for h2

    #pragma unroll
    for (int ci = 0; ci < 4; ++ci){
        const int ct = w * 4 + ci;
        f32x4 acc0 = {0.f, 0.f, 0.f, 0.f};
        f32x4 acc1 = {0.f, 0.f, 0.f, 0.f};
        const unsigned short* bp = w2t + (ct * 16 + lm) * 256 + lq * 8;
        #pragma unroll
        for (int kk = 0; kk < 8; ++kk){
            bf16x8 bfr = *(const bf16x8*)(bp + kk * 32);
            acc0 = __builtin_amdgcn_mfma_f32_16x16x32_bf16(afr[0][kk], bfr, acc0, 0, 0, 0);
            acc1 = __builtin_amdgcn_mfma_f32_16x16x32_bf16(afr[1][kk], bfr, acc1, 0, 0, 0);
        }
        float bb = b2[ct * 16 + lm];
        #pragma unroll
        for (int p = 0; p < 4; ++p){
            int r0 = lq * 4 + p;
            hbuf[r0 * 260 + ct * 16 + lm]        = f2bf(fmaxf(acc0[p] + bb, 0.f));
            hbuf[(16 + r0) * 260 + ct * 16 + lm] = f2bf(fmaxf(acc1[p] + bb, 0.f));
        }
    }
    __syncthreads();

    // phase 3: heads. thread t: row = t>>3, col segment = (t&7)*32
    const int prow = t >> 3;
    const int seg  = t & 7;
    float m0 = 0.f, m1 = 0.f, l0 = 0.f, l1 = 0.f;
    const ushort4* hr4 = (const ushort4*)&hbuf[prow * 260 + seg * 32];
    #pragma unroll
    for (int jj = 0; jj < 8; ++jj){
        ushort4 hv = hr4[jj];
        int c0 = seg * 32 + jj * 4;
        float4 wmA = *(const float4*)&Wmu[c0 * 2];
        float4 wmB = *(const float4*)&Wmu[c0 * 2 + 4];
        float4 wlA = *(const float4*)&Wls[c0 * 2];
        float4 wlB = *(const float4*)&Wls[c0 * 2 + 4];
        float h0 = bf2f(hv.x), h1 = bf2f(hv.y), h2 = bf2f(hv.z), h3 = bf2f(hv.w);
        m0 += h0 * wmA.x + h1 * wmA.z + h2 * wmB.x + h3 * wmB.z;
        m1 += h0 * wmA.y + h1 * wmA.w + h2 * wmB.y + h3 * wmB.w;
        l0 += h0 * wlA.x + h1 * wlA.z + h2 * wlB.x + h3 * wlB.z;
        l1 += h0 * wlA.y + h1 * wlA.w + h2 * wlB.y + h3 * wlB.w;
    }
    // 8-lane DPP partial sums: total lands in seg==7 lane of each group
    m0 = dpp_add<0x111, 0xF>(m0); m0 = dpp_add<0x112, 0xF>(m0); m0 = dpp_add<0x114, 0xF>(m0);
    m1 = dpp_add<0x111, 0xF>(m1); m1 = dpp_add<0x112, 0xF>(m1); m1 = dpp_add<0x114, 0xF>(m1);
    l0 = dpp_add<0x111, 0xF>(l0); l0 = dpp_add<0x112, 0xF>(l0); l0 = dpp_add<0x114, 0xF>(l0);
    l1 = dpp_add<0x111, 0xF>(l1); l1 = dpp_add<0x112, 0xF>(l1); l1 = dpp_add<0x114, 0xF>(l1);

    if (seg == 7){
        int row = row0 + prow;
        float n0 = noise[(size_t)row * 2 + 0];
        float n1 = noise[(size_t)row * 2 + 1];
        float lp = 0.f;
        {
            float mu = tanhf(m0 + bmu[0]);
            float ls = tanhf(l0 + bls[0]);
            ls = -20.f + 11.f * (ls + 1.f);
            float sd = expf(ls);
            float a = tanhf(mu + sd * n0);
            action_out[(size_t)row * 2 + 0] = a;
            lp += -0.5f * n0 * n0 - ls - 0.9189385332046727f - logf(1.f - a * a + 1e-7f);
        }
        {
            float mu = tanhf(m1 + bmu[1]);
            float ls = tanhf(l1 + bls[1]);
            ls = -20.f + 11.f * (ls + 1.f);
            float sd = expf(ls);
            float a = tanhf(mu + sd * n1);
            action_out[(size_t)row * 2 + 1] = a;
            lp += -0.5f * n1 * n1 - ls - 0.9189385332046727f - logf(1.f - a * a + 1e-7f);
        }
        logprob_out[row] = lp;
    }
}

extern "C" void kernel_launch(void* const* d_in, const int* in_sizes, int n_in,
                              void* d_out, int out_size, void* d_ws, size_t ws_size,
                              hipStream_t stream)
{
    (void)in_sizes; (void)n_in; (void)out_size; (void)ws_size;
    const float* state = (const float*)d_in[0];
    const float* noise = (const float*)d_in[1];
    const float* Wq  = (const float*)d_in[2];
    const float* Wk  = (const float*)d_in[3];
    const float* Wv  = (const float*)d_in[4];
    const float* W1  = (const float*)d_in[5];
    const float* b1  = (const float*)d_in[6];
    const float* W2  = (const float*)d_in[7];
    const float* b2  = (const float*)d_in[8];
    const float* Wmu = (const float*)d_in[9];
    const float* bmu = (const float*)d_in[10];
    const float* Wls = (const float*)d_in[11];
    const float* bls = (const float*)d_in[12];

    float* qk_ws = (float*)d_ws;                                  // 983040 f32
    unsigned short* w2t = (unsigned short*)(qk_ws + (size_t)NROWS * 15);  // 65536
    unsigned short* w1t = w2t + 65536;                            // 8192
    unsigned short* x0_ws = w1t + 8192;                           // NROWS*32

    float* action_out  = (float*)d_out;
    float* logprob_out = (float*)d_out + (size_t)NROWS * 2;

    prep_qk_kernel<<<513, 256, 0, stream>>>(W2, W1, state, Wq, Wk, w2t, w1t, qk_ws);
    attn_kernel<<<NROWS / 4, 256, 0, stream>>>(state, qk_ws, Wv, x0_ws);
    mlp_kernel<<<NROWS / MROWS, 256, 0, stream>>>(x0_ws, noise, w1t, b1, w2t, b2,
        Wmu, bmu, Wls, bls, action_out, logprob_out);
}

// Round 4
// 143.596 us; speedup vs baseline: 2.2241x; 1.3414x over previous
//
#include <hip/hip_runtime.h>
#include <math.h>

#define NROWS 65536   // B*T = 1024*64

typedef short bf16x8 __attribute__((ext_vector_type(8)));
typedef float f32x4  __attribute__((ext_vector_type(4)));

__device__ __forceinline__ unsigned short f2bf(float x){
    unsigned int u = __float_as_uint(x);
    u += 0x7FFFu + ((u >> 16) & 1u);      // RNE
    return (unsigned short)(u >> 16);
}

template<int CTRL, int RM>
__device__ __forceinline__ float dpp_add(float v){
    int m = __builtin_amdgcn_update_dpp(0, __float_as_int(v), CTRL, RM, 0xF, 1);
    return v + __int_as_float(m);
}
// sum within each 16-lane row; total lands in lane lm==15
__device__ __forceinline__ float rowsum16(float v){
    v = dpp_add<0x111, 0xF>(v);
    v = dpp_add<0x112, 0xF>(v);
    v = dpp_add<0x114, 0xF>(v);
    v = dpp_add<0x118, 0xF>(v);
    return v;
}

// ---- prep: transpose W2 -> w2t bf16 [col][k], W1 -> w1t bf16 [col][k pad 32] ----
__global__ __launch_bounds__(256) void prep_kernel(
    const float* __restrict__ W2, const float* __restrict__ W1,
    unsigned short* __restrict__ w2t, unsigned short* __restrict__ w1t)
{
    const int bx = blockIdx.x, t = threadIdx.x;
    if (bx < 256){
        w2t[t * 256 + bx] = f2bf(W2[bx * 256 + t]);
    } else {
        #pragma unroll
        for (int k = 0; k < 32; ++k)
            w1t[t * 32 + k] = (k < 23) ? f2bf(W1[k * 256 + t]) : (unsigned short)0;
    }
}

// ---- fused actor: one block per batch (64 agents) ----
__global__ __launch_bounds__(256) void actor_kernel(
    const float* __restrict__ state, const float* __restrict__ noise,
    const float* __restrict__ Wq, const float* __restrict__ Wk,
    const float* __restrict__ Wv,
    const unsigned short* __restrict__ w1t, const float* __restrict__ b1,
    const unsigned short* __restrict__ w2t, const float* __restrict__ b2,
    const float* __restrict__ Wmu, const float* __restrict__ bmu,
    const float* __restrict__ Wls, const float* __restrict__ bls,
    float* __restrict__ action_out, float* __restrict__ logprob_out)
{
    __shared__ float sLDS[64 * 9];                 // state, stride 9 (conflict-free per-lane)
    __shared__ float pjLDS[64 * 8];                // packed per-j: s0..3, sn, cs (uniform b128 reads)
    __shared__ float qkLDS[64 * 17];               // prescaled qk, stride 17
    __shared__ __align__(16) unsigned short x0LDS[64 * 40];   // x0 bf16, stride 40 (80B, 16B-aligned)
    __shared__ float headLDS[4 * 64 * 5];          // per-wave head partials, stride 5
    // union region: qLDS (f32 64*17) | mergeLDS (f32 4*64*25) | h1LDS (u16 64*264)
    __shared__ __align__(16) unsigned char uni[64 * 264 * 2];
    float* qLDS = (float*)uni;
    float* mergeLDS = (float*)uni;
    unsigned short* h1LDS = (unsigned short*)uni;

    const int t    = threadIdx.x;
    const int lane = t & 63;
    const int w    = t >> 6;
    const int lm   = lane & 15;
    const int lq   = lane >> 4;
    const int b    = blockIdx.x;

    // ---- phase 0: load state -> sLDS(stride 9) + pjLDS positions ----
    {
        float v0 = state[(size_t)b * 512 + t];
        float v1 = state[(size_t)b * 512 + t + 256];
        int r0 = t >> 3, c0 = t & 7;
        int r1 = (t + 256) >> 3, c1 = t & 7;
        sLDS[r0 * 9 + c0] = v0;
        sLDS[r1 * 9 + c1] = v1;
        if (c0 < 4) pjLDS[r0 * 8 + c0] = v0;
        if (c1 < 4) pjLDS[r1 * 8 + c1] = v1;
    }
    __syncthreads();

    // ---- phase 0b: per-row sincos + q = state@Wq ----
    {
        const int row = t & 63, part = t >> 6;
        if (part == 0){
            float ang = 1.5707963267948966f - sLDS[row * 9 + 7];
            float sn, cs;
            __sincosf(ang, &sn, &cs);
            pjLDS[row * 8 + 4] = sn;
            pjLDS[row * 8 + 5] = cs;
        } else {
            #pragma unroll
            for (int e = 0; e < 5; ++e){
                int m = (part - 1) * 5 + e;
                float acc = 0.f;
                #pragma unroll
                for (int d = 0; d < 8; ++d) acc += sLDS[row * 9 + d] * Wq[d * 15 + m];
                qLDS[row * 17 + m] = acc;
            }
        }
    }
    __syncthreads();

    // ---- phase 0c: qk = fold(q@Wk), prescaled by (1/sqrt5)*log2(e) ----
    {
        const int row = t & 63, part = t >> 6;
        #pragma unroll
        for (int e = 0; e < 4; ++e){
            int m = part * 4 + e;
            if (m < 15){
                int h = m / 5, f = m - h * 5;
                float acc = 0.f;
                #pragma unroll
                for (int kk = 0; kk < 5; ++kk)
                    acc += Wk[f * 15 + h * 5 + kk] * qLDS[row * 17 + h * 5 + kk];
                qkLDS[row * 17 + m] = acc * 0.64519834f;   // 0.4472136 * 1.4426950
            }
        }
    }
    __syncthreads();

    // ---- phase 1: attention, lane = i, wave w handles j in [w*16, w*16+16) ----
    {
        const int i = lane;
        float si0 = sLDS[i * 9 + 0], si1 = sLDS[i * 9 + 1];
        float si2 = sLDS[i * 9 + 2], si3 = sLDS[i * 9 + 3];
        float qkv[15];
        #pragma unroll
        for (int m = 0; m < 15; ++m) qkv[m] = qkLDS[i * 17 + m];

        float mh[3] = {-1e30f, -1e30f, -1e30f};
        float sh[3] = {0.f, 0.f, 0.f};
        float g[3][5];
        #pragma unroll
        for (int h = 0; h < 3; ++h)
            #pragma unroll
            for (int f = 0; f < 5; ++f) g[h][f] = 0.f;

        for (int jj = 0; jj < 16; ++jj){
            const int j = (w << 4) | jj;
            float4 pj = *(const float4*)&pjLDS[j * 8];       // uniform
            float sn = pjLDS[j * 8 + 4], cs = pjLDS[j * 8 + 5];
            float d0 = pj.x - si0, d1 = pj.y - si1, d2 = pj.z - si2, d3 = pj.w - si3;
            float xn0 = d0 * cs - d1 * sn, yn0 = d0 * sn + d1 * cs;
            float xn1 = d2 * cs - d3 * sn, yn1 = d2 * sn + d3 * cs;
            float r2v = xn0 * xn0 + yn0 * yn0;
            bool self = (j == i);
            float inv_r = self ? 0.f : rsqrtf(r2v);
            float rv = r2v * inv_r;
            float ex = exp2f(rv * 7.2134752f - 2.8853901f);  // e^(5r-2)
            float f4 = 1.f / (1.f + ex);
            float f0 = xn0 * inv_r, f1 = yn0 * inv_r;
            #pragma unroll
            for (int h = 0; h < 3; ++h){
                float sc = f0 * qkv[h*5] + f1 * qkv[h*5+1] + xn1 * qkv[h*5+2]
                         + yn1 * qkv[h*5+3] + f4 * qkv[h*5+4];
                sc = self ? -1e30f : sc;
                float mn = fmaxf(mh[h], sc);
                float e  = exp2f(sc - mn);
                float sca = exp2f(mh[h] - mn);
                mh[h] = mn;
                sh[h] = sh[h] * sca + e;
                g[h][0] = g[h][0] * sca + e * f0;
                g[h][1] = g[h][1] * sca + e * f1;
                g[h][2] = g[h][2] * sca + e * xn1;
                g[h][3] = g[h][3] * sca + e * yn1;
                g[h][4] = g[h][4] * sca + e * f4;
            }
        }
        #pragma unroll
        for (int h = 0; h < 3; ++h){
            float* mp = &mergeLDS[(w * 64 + i) * 25 + h * 8];
            mp[0] = mh[h];
            mp[1] = sh[h];
            #pragma unroll
            for (int f = 0; f < 5; ++f) mp[2 + f] = g[h][f];
        }
    }
    __syncthreads();

    // ---- phase 1b: merge 4 wave-partials, apply Wv, build x0 (bf16) ----
    if (t < 192){
        const int i = t & 63, h = t >> 6;
        float M = -1e30f;
        float pm[4], ps[4], pg[4][5];
        #pragma unroll
        for (int ww = 0; ww < 4; ++ww){
            const float* mp = &mergeLDS[(ww * 64 + i) * 25 + h * 8];
            pm[ww] = mp[0]; ps[ww] = mp[1];
            #pragma unroll
            for (int f = 0; f < 5; ++f) pg[ww][f] = mp[2 + f];
            M = fmaxf(M, pm[ww]);
        }
        float stot = 0.f, gt[5] = {0.f, 0.f, 0.f, 0.f, 0.f};
        #pragma unroll
        for (int ww = 0; ww < 4; ++ww){
            float sca = exp2f(pm[ww] - M);
            stot += ps[ww] * sca;
            #pragma unroll
            for (int f = 0; f < 5; ++f) gt[f] += pg[ww][f] * sca;
        }
        float inv = 1.f / stot;
        #pragma unroll
        for (int f = 0; f < 5; ++f) gt[f] *= inv;
        #pragma unroll
        for (int of = 0; of < 5; ++of){
            int m = h * 5 + of;
            float av = gt[0] * Wv[m] + gt[1] * Wv[15 + m] + gt[2] * Wv[30 + m]
                     + gt[3] * Wv[45 + m] + gt[4] * Wv[60 + m];
            x0LDS[i * 40 + m] = f2bf(av);
        }
    } else {
        const int i = t & 63;
        #pragma unroll
        for (int d = 0; d < 8; ++d) x0LDS[i * 40 + 15 + d] = f2bf(sLDS[i * 9 + d]);
        #pragma unroll
        for (int e = 23; e < 32; ++e) x0LDS[i * 40 + e] = 0;
    }
    __syncthreads();

    // ---- phase 2: h1 = relu(x0 @ W1 + b1) via MFMA, wave w owns coltiles w*4..w*4+3 ----
    {
        bf16x8 afr[4];
        #pragma unroll
        for (int rt = 0; rt < 4; ++rt)
            afr[rt] = *(const bf16x8*)&x0LDS[(rt * 16 + lm) * 40 + lq * 8];
        #pragma unroll
        for (int ci = 0; ci < 4; ++ci){
            const int ct = w * 4 + ci;
            bf16x8 bfr = *(const bf16x8*)&w1t[(ct * 16 + lm) * 32 + lq * 8];
            float bb = b1[ct * 16 + lm];
            #pragma unroll
            for (int rt = 0; rt < 4; ++rt){
                f32x4 c0 = {0.f, 0.f, 0.f, 0.f};
                c0 = __builtin_amdgcn_mfma_f32_16x16x32_bf16(afr[rt], bfr, c0, 0, 0, 0);
                #pragma unroll
                for (int p = 0; p < 4; ++p)
                    h1LDS[(rt * 16 + lq * 4 + p) * 264 + ct * 16 + lm] = f2bf(fmaxf(c0[p] + bb, 0.f));
            }
        }
    }
    __syncthreads();

    // ---- phase 3: h2 = relu(h1 @ W2 + b2) via MFMA; heads in-register ----
    {
        f32x4 acc[4][4];
        #pragma unroll
        for (int rt = 0; rt < 4; ++rt)
            #pragma unroll
            for (int ci = 0; ci < 4; ++ci) acc[rt][ci] = (f32x4){0.f, 0.f, 0.f, 0.f};

        #pragma unroll
        for (int kk = 0; kk < 8; ++kk){
            bf16x8 arf[4], brf[4];
            #pragma unroll
            for (int rt = 0; rt < 4; ++rt)
                arf[rt] = *(const bf16x8*)&h1LDS[(rt * 16 + lm) * 264 + kk * 32 + lq * 8];
            #pragma unroll
            for (int ci = 0; ci < 4; ++ci)
                brf[ci] = *(const bf16x8*)&w2t[((w * 4 + ci) * 16 + lm) * 256 + kk * 32 + lq * 8];
            #pragma unroll
            for (int rt = 0; rt < 4; ++rt)
                #pragma unroll
                for (int ci = 0; ci < 4; ++ci)
                    acc[rt][ci] = __builtin_amdgcn_mfma_f32_16x16x32_bf16(arf[rt], brf[ci], acc[rt][ci], 0, 0, 0);
        }

        float bb[4];
        float2 wm[4], wl[4];
        #pragma unroll
        for (int ci = 0; ci < 4; ++ci){
            int c = (w * 4 + ci) * 16 + lm;
            bb[ci] = b2[c];
            wm[ci] = *(const float2*)&Wmu[c * 2];
            wl[ci] = *(const float2*)&Wls[c * 2];
        }
        // partial head sums per (rt,p) row, reduce over lm (16 lanes)
        #pragma unroll
        for (int rt = 0; rt < 4; ++rt){
            #pragma unroll
            for (int p = 0; p < 4; ++p){
                float m0 = 0.f, m1 = 0.f, l0 = 0.f, l1 = 0.f;
                #pragma unroll
                for (int ci = 0; ci < 4; ++ci){
                    float hv = fmaxf(acc[rt][ci][p] + bb[ci], 0.f);
                    m0 += hv * wm[ci].x;
                    m1 += hv * wm[ci].y;
                    l0 += hv * wl[ci].x;
                    l1 += hv * wl[ci].y;
                }
                m0 = rowsum16(m0); m1 = rowsum16(m1);
                l0 = rowsum16(l0); l1 = rowsum16(l1);
                if (lm == 15){
                    int row = rt * 16 + lq * 4 + p;
                    float* hp = &headLDS[(w * 64 + row) * 5];
                    hp[0] = m0; hp[1] = m1; hp[2] = l0; hp[3] = l1;
                }
            }
        }
    }
    __syncthreads();

    // ---- phase 4: epilogue, 64 threads = 64 rows ----
    if (t < 64){
        const int row = t;
        float m0 = 0.f, m1 = 0.f, l0 = 0.f, l1 = 0.f;
        #pragma unroll
        for (int ww = 0; ww < 4; ++ww){
            const float* hp = &headLDS[(ww * 64 + row) * 5];
            m0 += hp[0]; m1 += hp[1]; l0 += hp[2]; l1 += hp[3];
        }
        const size_t grow = (size_t)b * 64 + row;
        float n0 = noise[grow * 2 + 0];
        float n1 = noise[grow * 2 + 1];
        float lp = 0.f;
        {
            float mu = tanhf(m0 + bmu[0]);
            float ls = tanhf(l0 + bls[0]);
            ls = -20.f + 11.f * (ls + 1.f);
            float sd = expf(ls);
            float a = tanhf(mu + sd * n0);
            action_out[grow * 2 + 0] = a;
            lp += -0.5f * n0 * n0 - ls - 0.9189385332046727f - logf(1.f - a * a + 1e-7f);
        }
        {
            float mu = tanhf(m1 + bmu[1]);
            float ls = tanhf(l1 + bls[1]);
            ls = -20.f + 11.f * (ls + 1.f);
            float sd = expf(ls);
            float a = tanhf(mu + sd * n1);
            action_out[grow * 2 + 1] = a;
            lp += -0.5f * n1 * n1 - ls - 0.9189385332046727f - logf(1.f - a * a + 1e-7f);
        }
        logprob_out[grow] = lp;
    }
}

extern "C" void kernel_launch(void* const* d_in, const int* in_sizes, int n_in,
                              void* d_out, int out_size, void* d_ws, size_t ws_size,
                              hipStream_t stream)
{
    (void)in_sizes; (void)n_in; (void)out_size; (void)ws_size;
    const float* state = (const float*)d_in[0];
    const float* noise = (const float*)d_in[1];
    const float* Wq  = (const float*)d_in[2];
    const float* Wk  = (const float*)d_in[3];
    const float* Wv  = (const float*)d_in[4];
    const float* W1  = (const float*)d_in[5];
    const float* b1  = (const float*)d_in[6];
    const float* W2  = (const float*)d_in[7];
    const float* b2  = (const float*)d_in[8];
    const float* Wmu = (const float*)d_in[9];
    const float* bmu = (const float*)d_in[10];
    const float* Wls = (const float*)d_in[11];
    const float* bls = (const float*)d_in[12];

    unsigned short* w2t = (unsigned short*)d_ws;   // 65536 bf16
    unsigned short* w1t = w2t + 65536;             // 8192 bf16

    float* action_out  = (float*)d_out;
    float* logprob_out = (float*)d_out + (size_t)NROWS * 2;

    prep_kernel<<<257, 256, 0, stream>>>(W2, W1, w2t, w1t);
    actor_kernel<<<1024, 256, 0, stream>>>(state, noise, Wq, Wk, Wv,
        w1t, b1, w2t, b2, Wmu, bmu, Wls, bls, action_out, logprob_out);
}

// Round 5
// 126.348 us; speedup vs baseline: 2.5277x; 1.1365x over previous
//
#include <hip/hip_runtime.h>
#include <math.h>

#define NROWS 65536   // B*T = 1024*64

typedef short bf16x8 __attribute__((ext_vector_type(8)));
typedef float f32x4  __attribute__((ext_vector_type(4)));

__device__ __forceinline__ unsigned short f2bf(float x){
    unsigned int u = __float_as_uint(x);
    u += 0x7FFFu + ((u >> 16) & 1u);      // RNE
    return (unsigned short)(u >> 16);
}

template<int CTRL, int RM>
__device__ __forceinline__ float dpp_add(float v){
    int m = __builtin_amdgcn_update_dpp(0, __float_as_int(v), CTRL, RM, 0xF, 1);
    return v + __int_as_float(m);
}
// sum within each 16-lane row; total lands in lane lm==15
__device__ __forceinline__ float rowsum16(float v){
    v = dpp_add<0x111, 0xF>(v);
    v = dpp_add<0x112, 0xF>(v);
    v = dpp_add<0x114, 0xF>(v);
    v = dpp_add<0x118, 0xF>(v);
    return v;
}

// ---- prep: weights -> MFMA B-fragment order (coalesced 16B/lane in hot loop) ----
// w2frag[((ct*8 + kk)*64 + lane)*8 + e] = W2[kk*32 + (lane>>4)*8 + e][ct*16 + (lane&15)]
// w1frag[(ct*64 + lane)*8 + e]          = k<23 ? W1[k][ct*16+(lane&15)] : 0,  k=(lane>>4)*8+e
__global__ __launch_bounds__(256) void prep_kernel(
    const float* __restrict__ W2, const float* __restrict__ W1,
    unsigned short* __restrict__ w2frag, unsigned short* __restrict__ w1frag)
{
    const int bx = blockIdx.x, t = threadIdx.x;
    if (bx < 128){
        const int ct = bx >> 3, kk = bx & 7;
        #pragma unroll
        for (int s = 0; s < 2; ++s){
            int f = t * 2 + s;            // [0,512)
            int lane = f >> 3, e = f & 7;
            int k = kk * 32 + (lane >> 4) * 8 + e;
            int c = ct * 16 + (lane & 15);
            w2frag[(size_t)(ct * 8 + kk) * 512 + f] = f2bf(W2[k * 256 + c]);
        }
    } else {
        #pragma unroll
        for (int s = 0; s < 32; ++s){
            int flat = t * 32 + s;        // [0,8192)
            int ct = flat >> 9, r = flat & 511;
            int lane = r >> 3, e = r & 7;
            int k = (lane >> 4) * 8 + e;
            int c = ct * 16 + (lane & 15);
            w1frag[flat] = (k < 23) ? f2bf(W1[k * 256 + c]) : (unsigned short)0;
        }
    }
}

// ---- fused actor: one block per batch, 512 threads (8 waves) ----
__global__ __launch_bounds__(512, 4) void actor_kernel(
    const float* __restrict__ state, const float* __restrict__ noise,
    const float* __restrict__ Wq, const float* __restrict__ Wk,
    const float* __restrict__ Wv,
    const unsigned short* __restrict__ w1frag, const float* __restrict__ b1,
    const unsigned short* __restrict__ w2frag, const float* __restrict__ b2,
    const float* __restrict__ Wmu, const float* __restrict__ bmu,
    const float* __restrict__ Wls, const float* __restrict__ bls,
    float* __restrict__ action_out, float* __restrict__ logprob_out)
{
    __shared__ float sLDS[64 * 9];                // state, stride 9
    __shared__ float pjLDS[64 * 8];               // per-j: s0..3, sn, cs
    __shared__ float qkLDS[64 * 17];              // prescaled qk
    __shared__ __align__(16) unsigned short x0LDS[64 * 40];
    __shared__ float headLDS[8 * 64 * 5];         // per-wave head partials
    // union: mergeLDS (f32 8*64*25 = 51200 B) | h1LDS (u16 64*264 = 33792 B)
    __shared__ __align__(16) unsigned char uni[8 * 64 * 25 * 4];
    float* mergeLDS = (float*)uni;
    unsigned short* h1LDS = (unsigned short*)uni;

    const int t    = threadIdx.x;
    const int lane = t & 63;
    const int w    = t >> 6;                      // 0..7
    const int lm   = lane & 15;
    const int lq   = lane >> 4;
    const int b    = blockIdx.x;

    // ---- phase 0: load state (coalesced, 1 float/thread) ----
    {
        float v = state[(size_t)b * 512 + t];
        int r = t >> 3, c = t & 7;
        sLDS[r * 9 + c] = v;
        if (c < 4) pjLDS[r * 8 + c] = v;
    }
    __syncthreads();

    // ---- phase 0bc: qk fold (waves 0-2, thread=(row,h)) + sincos (wave 7) ----
    if (t < 192){
        const int row = t & 63, h = t >> 6;
        float s[8];
        #pragma unroll
        for (int d = 0; d < 8; ++d) s[d] = sLDS[row * 9 + d];
        float q[5];
        #pragma unroll
        for (int e = 0; e < 5; ++e){
            int m = h * 5 + e;
            float acc = 0.f;
            #pragma unroll
            for (int d = 0; d < 8; ++d) acc += s[d] * Wq[d * 15 + m];
            q[e] = acc;
        }
        #pragma unroll
        for (int f = 0; f < 5; ++f){
            float acc = 0.f;
            #pragma unroll
            for (int kk = 0; kk < 5; ++kk) acc += Wk[f * 15 + h * 5 + kk] * q[kk];
            qkLDS[row * 17 + h * 5 + f] = acc * 0.64519834f;   // (1/sqrt5)*log2(e)
        }
    } else if (w == 7){
        const int row = lane;
        float ang = 1.5707963267948966f - sLDS[row * 9 + 7];
        float sn, cs;
        __sincosf(ang, &sn, &cs);
        pjLDS[row * 8 + 4] = sn;
        pjLDS[row * 8 + 5] = cs;
    }
    __syncthreads();

    // ---- phase 1: attention, lane=i; wave w: j in [w*8, w*8+8), 2 streams ----
    {
        const int i = lane;
        float si0 = sLDS[i * 9 + 0], si1 = sLDS[i * 9 + 1];
        float si2 = sLDS[i * 9 + 2], si3 = sLDS[i * 9 + 3];
        float qkv[15];
        #pragma unroll
        for (int m = 0; m < 15; ++m) qkv[m] = qkLDS[i * 17 + m];

        float mh[2][3], sh[2][3], g[2][3][5];
        #pragma unroll
        for (int st = 0; st < 2; ++st)
            #pragma unroll
            for (int h = 0; h < 3; ++h){
                mh[st][h] = -1e30f; sh[st][h] = 0.f;
                #pragma unroll
                for (int f = 0; f < 5; ++f) g[st][h][f] = 0.f;
            }

        #pragma unroll
        for (int jj = 0; jj < 4; ++jj){
            #pragma unroll
            for (int st = 0; st < 2; ++st){
                const int j = (w << 3) + jj * 2 + st;
                float4 pj = *(const float4*)&pjLDS[j * 8];
                float sn = pjLDS[j * 8 + 4], cs = pjLDS[j * 8 + 5];
                float d0 = pj.x - si0, d1 = pj.y - si1, d2 = pj.z - si2, d3 = pj.w - si3;
                float xn0 = d0 * cs - d1 * sn, yn0 = d0 * sn + d1 * cs;
                float xn1 = d2 * cs - d3 * sn, yn1 = d2 * sn + d3 * cs;
                float r2v = xn0 * xn0 + yn0 * yn0;
                bool self = (j == i);
                float inv_r = self ? 0.f : rsqrtf(r2v);
                float rv = r2v * inv_r;
                float ex = exp2f(rv * 7.2134752f - 2.8853901f);  // e^(5r-2)
                float f4 = 1.f / (1.f + ex);
                float f0 = xn0 * inv_r, f1 = yn0 * inv_r;
                #pragma unroll
                for (int h = 0; h < 3; ++h){
                    float sc = f0 * qkv[h*5] + f1 * qkv[h*5+1] + xn1 * qkv[h*5+2]
                             + yn1 * qkv[h*5+3] + f4 * qkv[h*5+4];
                    sc = self ? -1e30f : sc;
                    float mn = fmaxf(mh[st][h], sc);
                    float e  = exp2f(sc - mn);
                    float sca = exp2f(mh[st][h] - mn);
                    mh[st][h] = mn;
                    sh[st][h] = sh[st][h] * sca + e;
                    g[st][h][0] = g[st][h][0] * sca + e * f0;
                    g[st][h][1] = g[st][h][1] * sca + e * f1;
                    g[st][h][2] = g[st][h][2] * sca + e * xn1;
                    g[st][h][3] = g[st][h][3] * sca + e * yn1;
                    g[st][h][4] = g[st][h][4] * sca + e * f4;
                }
            }
        }
        // merge the two streams in-register, then one LDS record per (w,i)
        #pragma unroll
        for (int h = 0; h < 3; ++h){
            float M = fmaxf(mh[0][h], mh[1][h]);
            float sA = exp2f(mh[0][h] - M), sB = exp2f(mh[1][h] - M);
            float* mp = &mergeLDS[(w * 64 + i) * 25 + h * 8];
            mp[0] = M;
            mp[1] = sh[0][h] * sA + sh[1][h] * sB;
            #pragma unroll
            for (int f = 0; f < 5; ++f) mp[2 + f] = g[0][h][f] * sA + g[1][h][f] * sB;
        }
    }
    __syncthreads();

    // ---- phase 1b: merge 8 wave-partials, apply Wv, build x0 bf16 ----
    if (t < 192){
        const int i = t & 63, h = t >> 6;
        float M = -1e30f;
        float pm[8], ps[8], pg[8][5];
        #pragma unroll
        for (int ww = 0; ww < 8; ++ww){
            const float* mp = &mergeLDS[(ww * 64 + i) * 25 + h * 8];
            pm[ww] = mp[0]; ps[ww] = mp[1];
            #pragma unroll
            for (int f = 0; f < 5; ++f) pg[ww][f] = mp[2 + f];
            M = fmaxf(M, pm[ww]);
        }
        float stot = 0.f, gt[5] = {0.f, 0.f, 0.f, 0.f, 0.f};
        #pragma unroll
        for (int ww = 0; ww < 8; ++ww){
            float sca = exp2f(pm[ww] - M);
            stot += ps[ww] * sca;
            #pragma unroll
            for (int f = 0; f < 5; ++f) gt[f] += pg[ww][f] * sca;
        }
        float inv = 1.f / stot;
        #pragma unroll
        for (int f = 0; f < 5; ++f) gt[f] *= inv;
        #pragma unroll
        for (int of = 0; of < 5; ++of){
            int m = h * 5 + of;
            float av = gt[0] * Wv[m] + gt[1] * Wv[15 + m] + gt[2] * Wv[30 + m]
                     + gt[3] * Wv[45 + m] + gt[4] * Wv[60 + m];
            x0LDS[i * 40 + m] = f2bf(av);
        }
    } else if (w == 3){
        const int i = lane;
        #pragma unroll
        for (int d = 0; d < 8; ++d) x0LDS[i * 40 + 15 + d] = f2bf(sLDS[i * 9 + d]);
        #pragma unroll
        for (int e = 23; e < 32; ++e) x0LDS[i * 40 + e] = 0;
    }
    __syncthreads();

    // ---- phase 2: h1 = relu(x0 @ W1 + b1); wave w owns coltiles 2w, 2w+1 ----
    {
        bf16x8 afr[4];
        #pragma unroll
        for (int rt = 0; rt < 4; ++rt)
            afr[rt] = *(const bf16x8*)&x0LDS[(rt * 16 + lm) * 40 + lq * 8];
        #pragma unroll
        for (int ci = 0; ci < 2; ++ci){
            const int ct = w * 2 + ci;
            bf16x8 bfr = *(const bf16x8*)&w1frag[(size_t)ct * 512 + lane * 8];
            float bb = b1[ct * 16 + lm];
            #pragma unroll
            for (int rt = 0; rt < 4; ++rt){
                f32x4 c0 = {0.f, 0.f, 0.f, 0.f};
                c0 = __builtin_amdgcn_mfma_f32_16x16x32_bf16(afr[rt], bfr, c0, 0, 0, 0);
                #pragma unroll
                for (int p = 0; p < 4; ++p)
                    h1LDS[(rt * 16 + lq * 4 + p) * 264 + ct * 16 + lm] = f2bf(fmaxf(c0[p] + bb, 0.f));
            }
        }
    }
    __syncthreads();

    // ---- phase 3: h2 = relu(h1 @ W2 + b2); heads in-register ----
    {
        f32x4 acc[4][2];
        #pragma unroll
        for (int rt = 0; rt < 4; ++rt)
            #pragma unroll
            for (int ci = 0; ci < 2; ++ci) acc[rt][ci] = (f32x4){0.f, 0.f, 0.f, 0.f};

        #pragma unroll
        for (int kk = 0; kk < 8; ++kk){
            bf16x8 arf[4], brf[2];
            #pragma unroll
            for (int rt = 0; rt < 4; ++rt)
                arf[rt] = *(const bf16x8*)&h1LDS[(rt * 16 + lm) * 264 + kk * 32 + lq * 8];
            #pragma unroll
            for (int ci = 0; ci < 2; ++ci)
                brf[ci] = *(const bf16x8*)&w2frag[(size_t)((w * 2 + ci) * 8 + kk) * 512 + lane * 8];
            #pragma unroll
            for (int rt = 0; rt < 4; ++rt)
                #pragma unroll
                for (int ci = 0; ci < 2; ++ci)
                    acc[rt][ci] = __builtin_amdgcn_mfma_f32_16x16x32_bf16(arf[rt], brf[ci], acc[rt][ci], 0, 0, 0);
        }

        float bb[2];
        float2 wm[2], wl[2];
        #pragma unroll
        for (int ci = 0; ci < 2; ++ci){
            int c = (w * 2 + ci) * 16 + lm;
            bb[ci] = b2[c];
            wm[ci] = *(const float2*)&Wmu[c * 2];
            wl[ci] = *(const float2*)&Wls[c * 2];
        }
        #pragma unroll
        for (int rt = 0; rt < 4; ++rt){
            #pragma unroll
            for (int p = 0; p < 4; ++p){
                float m0 = 0.f, m1 = 0.f, l0 = 0.f, l1 = 0.f;
                #pragma unroll
                for (int ci = 0; ci < 2; ++ci){
                    float hv = fmaxf(acc[rt][ci][p] + bb[ci], 0.f);
                    m0 += hv * wm[ci].x;
                    m1 += hv * wm[ci].y;
                    l0 += hv * wl[ci].x;
                    l1 += hv * wl[ci].y;
                }
                m0 = rowsum16(m0); m1 = rowsum16(m1);
                l0 = rowsum16(l0); l1 = rowsum16(l1);
                if (lm == 15){
                    int row = rt * 16 + lq * 4 + p;
                    float* hp = &headLDS[(w * 64 + row) * 5];
                    hp[0] = m0; hp[1] = m1; hp[2] = l0; hp[3] = l1;
                }
            }
        }
    }
    __syncthreads();

    // ---- phase 4: epilogue, 64 threads = 64 rows ----
    if (t < 64){
        const int row = t;
        float m0 = 0.f, m1 = 0.f, l0 = 0.f, l1 = 0.f;
        #pragma unroll
        for (int ww = 0; ww < 8; ++ww){
            const float* hp = &headLDS[(ww * 64 + row) * 5];
            m0 += hp[0]; m1 += hp[1]; l0 += hp[2]; l1 += hp[3];
        }
        const size_t grow = (size_t)b * 64 + row;
        float n0 = noise[grow * 2 + 0];
        float n1 = noise[grow * 2 + 1];
        float lp = 0.f;
        {
            float mu = tanhf(m0 + bmu[0]);
            float ls = tanhf(l0 + bls[0]);
            ls = -20.f + 11.f * (ls + 1.f);
            float sd = expf(ls);
            float a = tanhf(mu + sd * n0);
            action_out[grow * 2 + 0] = a;
            lp += -0.5f * n0 * n0 - ls - 0.9189385332046727f - logf(1.f - a * a + 1e-7f);
        }
        {
            float mu = tanhf(m1 + bmu[1]);
            float ls = tanhf(l1 + bls[1]);
            ls = -20.f + 11.f * (ls + 1.f);
            float sd = expf(ls);
            float a = tanhf(mu + sd * n1);
            action_out[grow * 2 + 1] = a;
            lp += -0.5f * n1 * n1 - ls - 0.9189385332046727f - logf(1.f - a * a + 1e-7f);
        }
        logprob_out[grow] = lp;
    }
}

extern "C" void kernel_launch(void* const* d_in, const int* in_sizes, int n_in,
                              void* d_out, int out_size, void* d_ws, size_t ws_size,
                              hipStream_t stream)
{
    (void)in_sizes; (void)n_in; (void)out_size; (void)ws_size;
    const float* state = (const float*)d_in[0];
    const float* noise = (const float*)d_in[1];
    const float* Wq  = (const float*)d_in[2];
    const float* Wk  = (const float*)d_in[3];
    const float* Wv  = (const float*)d_in[4];
    const float* W1  = (const float*)d_in[5];
    const float* b1  = (const float*)d_in[6];
    const float* W2  = (const float*)d_in[7];
    const float* b2  = (const float*)d_in[8];
    const float* Wmu = (const float*)d_in[9];
    const float* bmu = (const float*)d_in[10];
    const float* Wls = (const float*)d_in[11];
    const float* bls = (const float*)d_in[12];

    unsigned short* w2frag = (unsigned short*)d_ws;   // 65536 bf16
    unsigned short* w1frag = w2frag + 65536;          // 8192 bf16

    float* action_out  = (float*)d_out;
    float* logprob_out = (float*)d_out + (size_t)NROWS * 2;

    prep_kernel<<<129, 256, 0, stream>>>(W2, W1, w2frag, w1frag);
    actor_kernel<<<1024, 512, 0, stream>>>(state, noise, Wq, Wk, Wv,
        w1frag, b1, w2frag, b2, Wmu, bmu, Wls, bls, action_out, logprob_out);
}